// Round 3
// baseline (511.637 us; speedup 1.0000x reference)
//
#include <hip/hip_runtime.h>
#include <hip/hip_bf16.h>

constexpr int D  = 128;
constexpr int H  = 8;
constexpr int DH = 16;
constexpr int NB = 16;   // nodes per GEMM block
constexpr int T  = 3;

// ---------- FiLM: gb[0:128]=gamma, gb[128:256]=beta ----------
__global__ void k_film(const float* __restrict__ gc, const float* __restrict__ fw,
                       const float* __restrict__ fb, float* __restrict__ gb, int C) {
  int j = threadIdx.x;  // 256 threads
  float acc = fb[j];
  for (int c = 0; c < C; ++c) acc += gc[c] * fw[c * 256 + j];
  gb[j] = acc;
}

// ---------- zero deg/cursor/tcnt/tcur, pnid = -1 ----------
__global__ void k_zero(int* __restrict__ deg, int* __restrict__ cursor,
                       int* __restrict__ pnid, int* __restrict__ tcnt,
                       int* __restrict__ tcur, int N, int P) {
  int i = blockIdx.x * blockDim.x + threadIdx.x;
  if (i < N) { deg[i] = 0; cursor[i] = 0; }
  if (i < P) pnid[i] = -1;
  if (i < T) { tcnt[i] = 0; tcur[i] = 0; }
}

// ---------- count in-degree + type histogram ----------
__global__ void k_count(const int* __restrict__ dst, const int* __restrict__ ntype,
                        int* __restrict__ deg, int* __restrict__ tcnt, int N, int E) {
  int i = blockIdx.x * blockDim.x + threadIdx.x;
  if (i < E) atomicAdd(deg + dst[i], 1);
  if (i < N) atomicAdd(tcnt + ntype[i], 1);
}

// ---------- exclusive prefix sum over deg -> off[0..N]; also toff from tcnt ----------
__global__ void k_scan(const int* __restrict__ deg, int* __restrict__ off,
                       const int* __restrict__ tcnt, int* __restrict__ toff,
                       int N, int E) {
  __shared__ int wsum[16];
  __shared__ int base_s;
  int tid = threadIdx.x;          // 0..1023
  int lane = tid & 63, w = tid >> 6;
  if (tid == 0) {
    base_s = 0;
    toff[0] = 0;
    for (int t = 0; t < T; ++t) toff[t + 1] = toff[t] + ((tcnt[t] + NB - 1) / NB) * NB;
  }
  __syncthreads();
  for (int start = 0; start < N; start += 1024) {
    int i = start + tid;
    int v = (i < N) ? deg[i] : 0;
    int x = v;
#pragma unroll
    for (int o = 1; o < 64; o <<= 1) {
      int y = __shfl_up(x, o);
      if (lane >= o) x += y;
    }
    if (lane == 63) wsum[w] = x;
    __syncthreads();
    if (w == 0 && lane < 16) {
      int s = wsum[lane];
#pragma unroll
      for (int o = 1; o < 16; o <<= 1) {
        int y = __shfl_up(s, o);
        if (lane >= o) s += y;
      }
      wsum[lane] = s;
    }
    __syncthreads();
    int waveoff = (w > 0) ? wsum[w - 1] : 0;
    if (i < N) off[i] = base_s + waveoff + x - v;
    __syncthreads();
    if (tid == 0) base_s += wsum[15];
    __syncthreads();
  }
  if (tid == 0) off[N] = E;
}

// ---------- scatter: edges -> CSR eid; nodes -> type-bucketed padded list ----------
__global__ void k_scatter(const int* __restrict__ dst, const int* __restrict__ ntype,
                          const int* __restrict__ off, const int* __restrict__ toff,
                          int* __restrict__ cursor, int* __restrict__ tcur,
                          int* __restrict__ eid, int* __restrict__ pnid, int N, int E) {
  int i = blockIdx.x * blockDim.x + threadIdx.x;
  if (i < E) {
    int d = dst[i];
    int pos = atomicAdd(cursor + d, 1);
    eid[off[d] + pos] = i;
  }
  if (i < N) {
    int t = ntype[i];
    int pos = atomicAdd(tcur + t, 1);
    pnid[toff[t] + pos] = i;
  }
}

// ---------- typed GEMM tile: k,q,v for 16 same-type nodes + head transforms ----------
__global__ void __launch_bounds__(128)
k_proj_t(const float* __restrict__ x, const int* __restrict__ pnid,
         const int* __restrict__ ntype,
         const float* __restrict__ Wk, const float* __restrict__ Wq,
         const float* __restrict__ Wv, const float* __restrict__ ra_,
         const float* __restrict__ rm_, const float* __restrict__ rp,
         float* __restrict__ ok, float* __restrict__ oqt, float* __restrict__ omt) {
  int b = blockIdx.x, j = threadIdx.x;  // 128 threads
  __shared__ float xs[NB][D];
  __shared__ float qs[NB][D], vs[NB][D];
  __shared__ int nid_s[NB];
  if (j < NB) nid_s[j] = pnid[b * NB + j];
  __syncthreads();
  // load x rows (0 for invalid slots)
  for (int idx = j; idx < NB * D; idx += 128) {
    int nn = idx >> 7, col = idx & 127;
    int nid = nid_s[nn];
    xs[nn][col] = (nid >= 0) ? x[(size_t)nid * D + col] : 0.f;
  }
  __syncthreads();
  int tfirst = -1;
#pragma unroll
  for (int nn = 0; nn < NB; ++nn) if (tfirst < 0 && nid_s[nn] >= 0) tfirst = ntype[nid_s[nn]];
  if (tfirst < 0) return;  // fully-padded block
  const float* wk = Wk + (size_t)tfirst * (D * D) + j;
  const float* wq = Wq + (size_t)tfirst * (D * D) + j;
  const float* wv = Wv + (size_t)tfirst * (D * D) + j;
  float ak[NB], aq[NB], av[NB];
#pragma unroll
  for (int nn = 0; nn < NB; ++nn) { ak[nn] = 0.f; aq[nn] = 0.f; av[nn] = 0.f; }
  for (int d = 0; d < D; ++d) {
    float wkv = wk[d * D], wqv = wq[d * D], wvv = wv[d * D];
#pragma unroll
    for (int nn = 0; nn < NB; ++nn) {
      float xv = xs[nn][d];
      ak[nn] += xv * wkv;
      aq[nn] += xv * wqv;
      av[nn] += xv * wvv;
    }
  }
#pragma unroll
  for (int nn = 0; nn < NB; ++nn) {
    int nid = nid_s[nn];
    if (nid >= 0) ok[(size_t)nid * D + j] = ak[nn];
    qs[nn][j] = aq[nn];
    vs[nn][j] = av[nn];
  }
  __syncthreads();
  // head transforms: qt[d] = rp*0.25*sum_z ra[h,d,z]*q[h*16+z]; mt[o]=sum_z rm[h,z,o]*v[h*16+z]
  int h = j >> 4, o = j & 15;
  float raz[DH], rmz[DH];
#pragma unroll
  for (int z = 0; z < DH; ++z) {
    raz[z] = ra_[h * 256 + o * 16 + z];
    rmz[z] = rm_[h * 256 + z * 16 + o];
  }
  float rph = rp[h] * 0.25f;
#pragma unroll
  for (int nn = 0; nn < NB; ++nn) {
    int nid = nid_s[nn];
    if (nid < 0) continue;
    float qa = 0.f, ma = 0.f;
#pragma unroll
    for (int z = 0; z < DH; ++z) {
      qa += raz[z] * qs[nn][h * DH + z];
      ma += rmz[z] * vs[nn][h * DH + z];
    }
    oqt[(size_t)nid * D + j] = qa * rph;
    omt[(size_t)nid * D + j] = ma;
  }
}

// ---------- per-node online-softmax aggregation over CSR edge list ----------
__global__ void k_agg(const int* __restrict__ eid, const int* __restrict__ off,
                      const int* __restrict__ src,
                      const float* __restrict__ kk, const float* __restrict__ qt,
                      const float* __restrict__ mt, float* __restrict__ hagg, int N) {
  int n = blockIdx.x;
  int j = threadIdx.x;  // 0..127
  float qv = qt[(size_t)n * D + j];
  int i0 = off[n], i1 = off[n + 1];
  float m = -INFINITY, ssum = 0.f, acc = 0.f;
  for (int i = i0; i < i1; ++i) {
    int e = eid[i];
    int sn = src[e];
    float kv = kk[(size_t)sn * D + j];
    float mv = mt[(size_t)sn * D + j];
    float p = kv * qv;  // reduce over 16 lanes of this head group
    p += __shfl_xor(p, 8);
    p += __shfl_xor(p, 4);
    p += __shfl_xor(p, 2);
    p += __shfl_xor(p, 1);
    float mn = fmaxf(m, p);
    float sc = __expf(m - mn);
    float wgt = __expf(p - mn);
    ssum = ssum * sc + wgt;
    acc = acc * sc + wgt * mv;
    m = mn;
  }
  hagg[(size_t)n * D + j] = (ssum > 0.f) ? acc / ssum : 0.f;
}

// ---------- typed GEMM tile for Wa + skip-mix + LayerNorm + residual + FiLM ----------
__global__ void __launch_bounds__(128)
k_out(const float* __restrict__ hagg, const int* __restrict__ pnid,
      const int* __restrict__ ntype, const float* __restrict__ Wa,
      const float* __restrict__ x, const float* __restrict__ skip,
      const float* __restrict__ ln_g, const float* __restrict__ ln_b,
      const float* __restrict__ gb, float* __restrict__ out) {
  int b = blockIdx.x, j = threadIdx.x;  // 128 threads
  __shared__ float hs[NB][D];
  __shared__ int nid_s[NB];
  __shared__ float red[2][NB][2];
  if (j < NB) nid_s[j] = pnid[b * NB + j];
  __syncthreads();
  for (int idx = j; idx < NB * D; idx += 128) {
    int nn = idx >> 7, col = idx & 127;
    int nid = nid_s[nn];
    hs[nn][col] = (nid >= 0) ? hagg[(size_t)nid * D + col] : 0.f;
  }
  __syncthreads();
  int tfirst = -1;
#pragma unroll
  for (int nn = 0; nn < NB; ++nn) if (tfirst < 0 && nid_s[nn] >= 0) tfirst = ntype[nid_s[nn]];
  if (tfirst < 0) return;
  const float* wp = Wa + (size_t)tfirst * (D * D) + j;
  float acc[NB];
#pragma unroll
  for (int nn = 0; nn < NB; ++nn) acc[nn] = 0.f;
  for (int d = 0; d < D; ++d) {
    float wv = wp[d * D];
#pragma unroll
    for (int nn = 0; nn < NB; ++nn) acc[nn] += hs[nn][d] * wv;
  }
  float alpha = 1.f / (1.f + __expf(-skip[tfirst]));
  int w = j >> 6;
  float hv[NB];
#pragma unroll
  for (int nn = 0; nn < NB; ++nn) {
    int nid = nid_s[nn];
    float xv = (nid >= 0) ? x[(size_t)nid * D + j] : 0.f;
    hv[nn] = (nid >= 0) ? (acc[nn] * alpha + xv * (1.f - alpha)) : 0.f;
    float s1 = hv[nn], s2 = hv[nn] * hv[nn];
#pragma unroll
    for (int o = 1; o < 64; o <<= 1) {
      s1 += __shfl_xor(s1, o);
      s2 += __shfl_xor(s2, o);
    }
    if ((j & 63) == 0) { red[w][nn][0] = s1; red[w][nn][1] = s2; }
  }
  __syncthreads();
  float gj = ln_g[j], bj = ln_b[j], gmj = gb[j], gbj = gb[D + j];
#pragma unroll
  for (int nn = 0; nn < NB; ++nn) {
    int nid = nid_s[nn];
    if (nid < 0) continue;
    float mu = (red[0][nn][0] + red[1][nn][0]) * (1.f / D);
    float m2 = (red[0][nn][1] + red[1][nn][1]) * (1.f / D);
    float var = m2 - mu * mu;
    float xv = x[(size_t)nid * D + j];
    float y = (hv[nn] - mu) * rsqrtf(var + 1e-5f) * gj + bj + xv;
    out[(size_t)nid * D + j] = gmj * y + gbj;
  }
}

extern "C" void kernel_launch(void* const* d_in, const int* in_sizes, int n_in,
                              void* d_out, int out_size, void* d_ws, size_t ws_size,
                              hipStream_t stream) {
  const float* x       = (const float*)d_in[0];
  const float* gc      = (const float*)d_in[1];
  const float* Wk      = (const float*)d_in[2];
  const float* Wq      = (const float*)d_in[3];
  const float* Wv      = (const float*)d_in[4];
  const float* rel_att = (const float*)d_in[5];
  const float* rel_msg = (const float*)d_in[6];
  const float* rel_pri = (const float*)d_in[7];
  const float* Wa      = (const float*)d_in[8];
  const float* skip    = (const float*)d_in[9];
  const float* ln_g    = (const float*)d_in[10];
  const float* ln_b    = (const float*)d_in[11];
  const float* fw      = (const float*)d_in[12];
  const float* fb      = (const float*)d_in[13];
  const int* ntype     = (const int*)d_in[14];
  const int* src       = (const int*)d_in[15];
  const int* dst       = (const int*)d_in[16];
  float* out = (float*)d_out;

  int N = in_sizes[0] / D;
  int C = in_sizes[1];
  int E = in_sizes[15];

  int gridP = (N + NB - 1) / NB + T;  // upper bound on padded tiles
  int P = gridP * NB;                 // padded node-list size

  float* ws = (float*)d_ws;
  size_t nD = (size_t)N * D;
  float* wk_   = ws;              // N*128   k
  float* wqt   = wk_ + nD;        // N*128   qt (scaled)
  float* wmt   = wqt + nD;        // N*128   mt
  float* whagg = wmt + nD;        // N*128   h_agg
  float* wgb   = whagg + nD;      // 256     gamma|beta
  int*   deg    = (int*)(wgb + 256);  // N
  int*   off    = deg + N;            // N+1
  int*   cursor = off + N + 1;        // N
  int*   eid    = cursor + N;         // E
  int*   tcnt   = eid + E;            // T
  int*   tcur   = tcnt + T;           // T
  int*   toff   = tcur + T;           // T+1
  int*   pnid   = toff + T + 1;       // P

  int mNE = (E > N) ? E : N;
  int mNP = (N > P) ? N : P;
  k_film<<<1, 2 * D, 0, stream>>>(gc, fw, fb, wgb, C);
  k_zero<<<(mNP + 255) / 256, 256, 0, stream>>>(deg, cursor, pnid, tcnt, tcur, N, P);
  k_count<<<(mNE + 255) / 256, 256, 0, stream>>>(dst, ntype, deg, tcnt, N, E);
  k_scan<<<1, 1024, 0, stream>>>(deg, off, tcnt, toff, N, E);
  k_scatter<<<(mNE + 255) / 256, 256, 0, stream>>>(dst, ntype, off, toff, cursor,
                                                   tcur, eid, pnid, N, E);
  k_proj_t<<<gridP, 128, 0, stream>>>(x, pnid, ntype, Wk, Wq, Wv, rel_att, rel_msg,
                                      rel_pri, wk_, wqt, wmt);
  k_agg<<<N, D, 0, stream>>>(eid, off, src, wk_, wqt, wmt, whagg, N);
  k_out<<<gridP, 128, 0, stream>>>(whagg, pnid, ntype, Wa, x, skip, ln_g, ln_b,
                                   wgb, out);
}

// Round 5
// 241.567 us; speedup vs baseline: 2.1180x; 2.1180x over previous
//
#include <hip/hip_runtime.h>
#include <hip/hip_bf16.h>

constexpr int D  = 128;
constexpr int H  = 8;
constexpr int DH = 16;
constexpr int NB = 16;   // nodes per GEMM block
constexpr int T  = 3;

// ---------- FiLM: gb[0:128]=gamma, gb[128:256]=beta ----------
__global__ void k_film(const float* __restrict__ gc, const float* __restrict__ fw,
                       const float* __restrict__ fb, float* __restrict__ gb, int C) {
  int j = threadIdx.x;  // 256 threads
  float acc = fb[j];
  for (int c = 0; c < C; ++c) acc += gc[c] * fw[c * 256 + j];
  gb[j] = acc;
}

// ---------- zero deg/cursor/tcnt/tcur, pnid = -1 ----------
__global__ void k_zero(int* __restrict__ deg, int* __restrict__ cursor,
                       int* __restrict__ pnid, int* __restrict__ tcnt,
                       int* __restrict__ tcur, int N, int P) {
  int i = blockIdx.x * blockDim.x + threadIdx.x;
  if (i < N) { deg[i] = 0; cursor[i] = 0; }
  if (i < P) pnid[i] = -1;
  if (i < T) { tcnt[i] = 0; tcur[i] = 0; }
}

// ---------- count in-degree + type histogram (wave-aggregated) ----------
__global__ void k_count(const int* __restrict__ dst, const int* __restrict__ ntype,
                        int* __restrict__ deg, int* __restrict__ tcnt, int N, int E) {
  int i = blockIdx.x * blockDim.x + threadIdx.x;
  if (i < E) atomicAdd(deg + dst[i], 1);
  int t = (i < N) ? ntype[i] : -1;
  int lane = threadIdx.x & 63;
#pragma unroll
  for (int tt = 0; tt < T; ++tt) {
    unsigned long long mask = __ballot(t == tt);
    int cnt = __popcll(mask);
    if (cnt > 0 && lane == (__ffsll((long long)mask) - 1))
      atomicAdd(tcnt + tt, cnt);
  }
}

// ---------- exclusive prefix sum over deg -> off[0..N]; also toff from tcnt ----------
__global__ void k_scan(const int* __restrict__ deg, int* __restrict__ off,
                       const int* __restrict__ tcnt, int* __restrict__ toff,
                       int N, int E) {
  __shared__ int wsum[16];
  __shared__ int base_s;
  int tid = threadIdx.x;          // 0..1023
  int lane = tid & 63, w = tid >> 6;
  if (tid == 0) {
    base_s = 0;
    toff[0] = 0;
    for (int t = 0; t < T; ++t) toff[t + 1] = toff[t] + ((tcnt[t] + NB - 1) / NB) * NB;
  }
  __syncthreads();
  for (int start = 0; start < N; start += 1024) {
    int i = start + tid;
    int v = (i < N) ? deg[i] : 0;
    int x = v;
#pragma unroll
    for (int o = 1; o < 64; o <<= 1) {
      int y = __shfl_up(x, o);
      if (lane >= o) x += y;
    }
    if (lane == 63) wsum[w] = x;
    __syncthreads();
    if (w == 0 && lane < 16) {
      int s = wsum[lane];
#pragma unroll
      for (int o = 1; o < 16; o <<= 1) {
        int y = __shfl_up(s, o);
        if (lane >= o) s += y;
      }
      wsum[lane] = s;
    }
    __syncthreads();
    int waveoff = (w > 0) ? wsum[w - 1] : 0;
    if (i < N) off[i] = base_s + waveoff + x - v;
    __syncthreads();
    if (tid == 0) base_s += wsum[15];
    __syncthreads();
  }
  if (tid == 0) off[N] = E;
}

// ---------- scatter: edges -> CSR eid; nodes -> type buckets (wave-aggregated) ----------
__global__ void k_scatter(const int* __restrict__ dst, const int* __restrict__ ntype,
                          const int* __restrict__ off, const int* __restrict__ toff,
                          int* __restrict__ cursor, int* __restrict__ tcur,
                          int* __restrict__ eid, int* __restrict__ pnid, int N, int E) {
  int i = blockIdx.x * blockDim.x + threadIdx.x;
  if (i < E) {
    int d = dst[i];
    int pos = atomicAdd(cursor + d, 1);
    eid[off[d] + pos] = i;
  }
  int t = (i < N) ? ntype[i] : -1;
  int lane = threadIdx.x & 63;
#pragma unroll
  for (int tt = 0; tt < T; ++tt) {
    unsigned long long mask = __ballot(t == tt);
    int cnt = __popcll(mask);
    if (cnt == 0) continue;
    int leader = __ffsll((long long)mask) - 1;
    int base = 0;
    if (lane == leader) base = atomicAdd(tcur + tt, cnt);
    base = __shfl(base, leader);
    if (t == tt) {
      int rank = __popcll(mask & ((1ull << lane) - 1ull));
      pnid[toff[tt] + base + rank] = i;
    }
  }
}

// ---------- typed GEMM tile: k,q,v for 16 same-type nodes + head transforms ----------
__global__ void __launch_bounds__(128)
k_proj_t(const float* __restrict__ x, const int* __restrict__ pnid,
         const int* __restrict__ ntype,
         const float* __restrict__ Wk, const float* __restrict__ Wq,
         const float* __restrict__ Wv, const float* __restrict__ ra_,
         const float* __restrict__ rm_, const float* __restrict__ rp,
         float* __restrict__ ok, float* __restrict__ oqt, float* __restrict__ omt) {
  int b = blockIdx.x, j = threadIdx.x;  // 128 threads
  __shared__ float xs[NB][D];
  __shared__ float qs[NB][D], vs[NB][D];
  __shared__ int nid_s[NB];
  if (j < NB) nid_s[j] = pnid[b * NB + j];
  __syncthreads();
  for (int idx = j; idx < NB * D; idx += 128) {
    int nn = idx >> 7, col = idx & 127;
    int nid = nid_s[nn];
    xs[nn][col] = (nid >= 0) ? x[(size_t)nid * D + col] : 0.f;
  }
  __syncthreads();
  int tfirst = -1;
#pragma unroll
  for (int nn = 0; nn < NB; ++nn) if (tfirst < 0 && nid_s[nn] >= 0) tfirst = ntype[nid_s[nn]];
  if (tfirst < 0) return;  // fully-padded block
  const float* wk = Wk + (size_t)tfirst * (D * D) + j;
  const float* wq = Wq + (size_t)tfirst * (D * D) + j;
  const float* wv = Wv + (size_t)tfirst * (D * D) + j;
  float ak[NB], aq[NB], av[NB];
#pragma unroll
  for (int nn = 0; nn < NB; ++nn) { ak[nn] = 0.f; aq[nn] = 0.f; av[nn] = 0.f; }
  for (int d = 0; d < D; ++d) {
    float wkv = wk[d * D], wqv = wq[d * D], wvv = wv[d * D];
#pragma unroll
    for (int nn = 0; nn < NB; ++nn) {
      float xv = xs[nn][d];
      ak[nn] += xv * wkv;
      aq[nn] += xv * wqv;
      av[nn] += xv * wvv;
    }
  }
#pragma unroll
  for (int nn = 0; nn < NB; ++nn) {
    int nid = nid_s[nn];
    if (nid >= 0) ok[(size_t)nid * D + j] = ak[nn];
    qs[nn][j] = aq[nn];
    vs[nn][j] = av[nn];
  }
  __syncthreads();
  int h = j >> 4, o = j & 15;
  float raz[DH], rmz[DH];
#pragma unroll
  for (int z = 0; z < DH; ++z) {
    raz[z] = ra_[h * 256 + o * 16 + z];
    rmz[z] = rm_[h * 256 + z * 16 + o];
  }
  float rph = rp[h] * 0.25f;
#pragma unroll
  for (int nn = 0; nn < NB; ++nn) {
    int nid = nid_s[nn];
    if (nid < 0) continue;
    float qa = 0.f, ma = 0.f;
#pragma unroll
    for (int z = 0; z < DH; ++z) {
      qa += raz[z] * qs[nn][h * DH + z];
      ma += rmz[z] * vs[nn][h * DH + z];
    }
    oqt[(size_t)nid * D + j] = qa * rph;
    omt[(size_t)nid * D + j] = ma;
  }
}

// ---------- per-node online-softmax aggregation (2-way unrolled) ----------
__global__ void k_agg(const int* __restrict__ eid, const int* __restrict__ off,
                      const int* __restrict__ src,
                      const float* __restrict__ kk, const float* __restrict__ qt,
                      const float* __restrict__ mt, float* __restrict__ hagg, int N) {
  int n = blockIdx.x;
  int j = threadIdx.x;  // 0..127
  float qv = qt[(size_t)n * D + j];
  int i0 = off[n], i1 = off[n + 1];
  float m = -INFINITY, ssum = 0.f, acc = 0.f;
  int i = i0;
  for (; i + 2 <= i1; i += 2) {
    int e0 = eid[i], e1 = eid[i + 1];
    int s0 = src[e0], s1 = src[e1];
    float kv0 = kk[(size_t)s0 * D + j], mv0 = mt[(size_t)s0 * D + j];
    float kv1 = kk[(size_t)s1 * D + j], mv1 = mt[(size_t)s1 * D + j];
    float p0 = kv0 * qv, p1 = kv1 * qv;
#pragma unroll
    for (int o = 8; o >= 1; o >>= 1) {
      p0 += __shfl_xor(p0, o);
      p1 += __shfl_xor(p1, o);
    }
    float mn = fmaxf(m, fmaxf(p0, p1));
    float sc = __expf(m - mn);
    float w0 = __expf(p0 - mn), w1 = __expf(p1 - mn);
    ssum = ssum * sc + w0 + w1;
    acc = acc * sc + w0 * mv0 + w1 * mv1;
    m = mn;
  }
  if (i < i1) {
    int e = eid[i];
    int sn = src[e];
    float kv = kk[(size_t)sn * D + j];
    float mv = mt[(size_t)sn * D + j];
    float p = kv * qv;
#pragma unroll
    for (int o = 8; o >= 1; o >>= 1) p += __shfl_xor(p, o);
    float mn = fmaxf(m, p);
    float sc = __expf(m - mn);
    float wgt = __expf(p - mn);
    ssum = ssum * sc + wgt;
    acc = acc * sc + wgt * mv;
    m = mn;
  }
  hagg[(size_t)n * D + j] = (ssum > 0.f) ? acc / ssum : 0.f;
}

// ---------- typed GEMM tile for Wa + skip-mix + LayerNorm + residual + FiLM ----------
__global__ void __launch_bounds__(128)
k_out(const float* __restrict__ hagg, const int* __restrict__ pnid,
      const int* __restrict__ ntype, const float* __restrict__ Wa,
      const float* __restrict__ x, const float* __restrict__ skip,
      const float* __restrict__ ln_g, const float* __restrict__ ln_b,
      const float* __restrict__ gb, float* __restrict__ out) {
  int b = blockIdx.x, j = threadIdx.x;  // 128 threads
  __shared__ float hs[NB][D];
  __shared__ int nid_s[NB];
  __shared__ float red[2][NB][2];
  if (j < NB) nid_s[j] = pnid[b * NB + j];
  __syncthreads();
  for (int idx = j; idx < NB * D; idx += 128) {
    int nn = idx >> 7, col = idx & 127;
    int nid = nid_s[nn];
    hs[nn][col] = (nid >= 0) ? hagg[(size_t)nid * D + col] : 0.f;
  }
  __syncthreads();
  int tfirst = -1;
#pragma unroll
  for (int nn = 0; nn < NB; ++nn) if (tfirst < 0 && nid_s[nn] >= 0) tfirst = ntype[nid_s[nn]];
  if (tfirst < 0) return;
  const float* wp = Wa + (size_t)tfirst * (D * D) + j;
  float acc[NB];
#pragma unroll
  for (int nn = 0; nn < NB; ++nn) acc[nn] = 0.f;
  for (int d = 0; d < D; ++d) {
    float wv = wp[d * D];
#pragma unroll
    for (int nn = 0; nn < NB; ++nn) acc[nn] += hs[nn][d] * wv;
  }
  float alpha = 1.f / (1.f + __expf(-skip[tfirst]));
  int w = j >> 6;
  float hv[NB];
#pragma unroll
  for (int nn = 0; nn < NB; ++nn) {
    int nid = nid_s[nn];
    float xv = (nid >= 0) ? x[(size_t)nid * D + j] : 0.f;
    hv[nn] = (nid >= 0) ? (acc[nn] * alpha + xv * (1.f - alpha)) : 0.f;
    float s1 = hv[nn], s2 = hv[nn] * hv[nn];
#pragma unroll
    for (int o = 1; o < 64; o <<= 1) {
      s1 += __shfl_xor(s1, o);
      s2 += __shfl_xor(s2, o);
    }
    if ((j & 63) == 0) { red[w][nn][0] = s1; red[w][nn][1] = s2; }
  }
  __syncthreads();
  float gj = ln_g[j], bj = ln_b[j], gmj = gb[j], gbj = gb[D + j];
#pragma unroll
  for (int nn = 0; nn < NB; ++nn) {
    int nid = nid_s[nn];
    if (nid < 0) continue;
    float mu = (red[0][nn][0] + red[1][nn][0]) * (1.f / D);
    float m2 = (red[0][nn][1] + red[1][nn][1]) * (1.f / D);
    float var = m2 - mu * mu;
    float xv = x[(size_t)nid * D + j];
    float y = (hv[nn] - mu) * rsqrtf(var + 1e-5f) * gj + bj + xv;
    out[(size_t)nid * D + j] = gmj * y + gbj;
  }
}

extern "C" void kernel_launch(void* const* d_in, const int* in_sizes, int n_in,
                              void* d_out, int out_size, void* d_ws, size_t ws_size,
                              hipStream_t stream) {
  const float* x       = (const float*)d_in[0];
  const float* gc      = (const float*)d_in[1];
  const float* Wk      = (const float*)d_in[2];
  const float* Wq      = (const float*)d_in[3];
  const float* Wv      = (const float*)d_in[4];
  const float* rel_att = (const float*)d_in[5];
  const float* rel_msg = (const float*)d_in[6];
  const float* rel_pri = (const float*)d_in[7];
  const float* Wa      = (const float*)d_in[8];
  const float* skip    = (const float*)d_in[9];
  const float* ln_g    = (const float*)d_in[10];
  const float* ln_b    = (const float*)d_in[11];
  const float* fw      = (const float*)d_in[12];
  const float* fb      = (const float*)d_in[13];
  const int* ntype     = (const int*)d_in[14];
  const int* src       = (const int*)d_in[15];
  const int* dst       = (const int*)d_in[16];
  float* out = (float*)d_out;

  int N = in_sizes[0] / D;
  int C = in_sizes[1];
  int E = in_sizes[15];

  int gridP = (N + NB - 1) / NB + T;  // upper bound on padded tiles
  int P = gridP * NB;                 // padded node-list size

  float* ws = (float*)d_ws;
  size_t nD = (size_t)N * D;
  float* wk_   = ws;              // N*128   k
  float* wqt   = wk_ + nD;        // N*128   qt (scaled)
  float* wmt   = wqt + nD;        // N*128   mt
  float* whagg = wmt + nD;        // N*128   h_agg
  float* wgb   = whagg + nD;      // 256     gamma|beta
  int*   deg    = (int*)(wgb + 256);  // N
  int*   off    = deg + N;            // N+1
  int*   cursor = off + N + 1;        // N
  int*   eid    = cursor + N;         // E
  int*   tcnt   = eid + E;            // T
  int*   tcur   = tcnt + T;           // T
  int*   toff   = tcur + T;           // T+1
  int*   pnid   = toff + T + 1;       // P

  int mNE = (E > N) ? E : N;
  int mNP = (N > P) ? N : P;
  k_film<<<1, 2 * D, 0, stream>>>(gc, fw, fb, wgb, C);
  k_zero<<<(mNP + 255) / 256, 256, 0, stream>>>(deg, cursor, pnid, tcnt, tcur, N, P);
  k_count<<<(mNE + 255) / 256, 256, 0, stream>>>(dst, ntype, deg, tcnt, N, E);
  k_scan<<<1, 1024, 0, stream>>>(deg, off, tcnt, toff, N, E);
  k_scatter<<<(mNE + 255) / 256, 256, 0, stream>>>(dst, ntype, off, toff, cursor,
                                                   tcur, eid, pnid, N, E);
  k_proj_t<<<gridP, 128, 0, stream>>>(x, pnid, ntype, Wk, Wq, Wv, rel_att, rel_msg,
                                      rel_pri, wk_, wqt, wmt);
  k_agg<<<N, D, 0, stream>>>(eid, off, src, wk_, wqt, wmt, whagg, N);
  k_out<<<gridP, 128, 0, stream>>>(whagg, pnid, ntype, Wa, x, skip, ln_g, ln_b,
                                   wgb, out);
}